// Round 12
// baseline (164.105 us; speedup 1.0000x reference)
//
#include <hip/hip_runtime.h>
#include <math.h>

#define N_NODES 50000
#define N_EDGES 600000
#define DIM 128
#define BCAP 64   // bucket capacity; P(Poisson(12) > 64) ~ 1e-28

typedef __attribute__((ext_vector_type(8))) short bf16x8;
typedef __attribute__((ext_vector_type(4))) float f32x4;

// float -> bf16 bits, round-to-nearest-even (values are finite; no NaN path)
static __device__ __forceinline__ short f2bf(float f) {
    unsigned u = __float_as_uint(f);
    unsigned r = (u + 0x7FFFu + ((u >> 16) & 1u)) >> 16;
    return (short)r;
}

// unpack one u32 (two bf16) -> two floats
#define UNPK(w, d0, d1)                         \
    d0 = __uint_as_float((w) << 16);            \
    d1 = __uint_as_float((w) & 0xFFFF0000u);

// sum across each 16-lane row via DPP (VALU pipe; no ds_swizzle / LDS latency).
#define DPPADD(x, ctrl)                                                          \
    x += __int_as_float(__builtin_amdgcn_mov_dpp(__float_as_int(x), ctrl,        \
                                                 0xF, 0xF, true));
static __device__ __forceinline__ float row_sum16(float x) {
    DPPADD(x, 0xB1)    // quad_perm [1,0,3,2]  (xor 1)
    DPPADD(x, 0x4E)    // quad_perm [2,3,0,1]  (xor 2)
    DPPADD(x, 0x141)   // row_half_mirror      (fold quads within 8)
    DPPADD(x, 0x140)   // row_mirror           (fold 8-halves within 16)
    return x;
}

// ---------------- prep: zero counters/cursors + convert W to bf16 (native [n][k] layout)
__global__ __launch_bounds__(256) void prep_kernel(const float* __restrict__ W,
                                                   unsigned short* __restrict__ Wb,
                                                   int* __restrict__ cur,
                                                   int* __restrict__ cnt) {
    int gid = blockIdx.x * 256 + threadIdx.x;
    if (gid < N_NODES) {
        cur[gid] = 0;
        cnt[gid] = 0;
    }
    if (gid < DIM * DIM) Wb[gid] = (unsigned short)f2bf(W[gid]);
}

// ---------------- bucket fill (fast path): lst[d*BCAP + pos] = src id
__global__ __launch_bounds__(256) void bfill_kernel(const int* __restrict__ src,
                                                    const int* __restrict__ dst,
                                                    int* __restrict__ cur,
                                                    int* __restrict__ lst) {
    int i = blockIdx.x * 256 + threadIdx.x;
    if (i >= N_EDGES) return;
    int d = dst[i];
    int pos = atomicAdd(cur + d, 1);
    if (pos < BCAP) lst[d * BCAP + pos] = src[i];
}

// ---------------- CSR fallback path: count / scan / fill (stores src ids)
__global__ __launch_bounds__(256) void count_kernel(const int* __restrict__ dst,
                                                    int* __restrict__ cnt) {
    int i = blockIdx.x * 256 + threadIdx.x;
    if (i < N_EDGES) atomicAdd(cnt + dst[i], 1);
}

__global__ __launch_bounds__(256) void scan_a(const int* __restrict__ cnt,
                                              int* __restrict__ incl,
                                              int* __restrict__ bsum) {
    __shared__ int s[256];
    int i = blockIdx.x * 256 + threadIdx.x;
    s[threadIdx.x] = (i < N_NODES) ? cnt[i] : 0;
    __syncthreads();
    #pragma unroll
    for (int off = 1; off < 256; off <<= 1) {
        int t = (threadIdx.x >= off) ? s[threadIdx.x - off] : 0;
        __syncthreads();
        s[threadIdx.x] += t;
        __syncthreads();
    }
    if (i < N_NODES) incl[i] = s[threadIdx.x];
    if (threadIdx.x == 255) bsum[blockIdx.x] = s[255];
}

__global__ __launch_bounds__(256) void scan_b(int* __restrict__ bsum, int nb) {
    __shared__ int s[256];
    s[threadIdx.x] = (threadIdx.x < nb) ? bsum[threadIdx.x] : 0;
    __syncthreads();
    #pragma unroll
    for (int off = 1; off < 256; off <<= 1) {
        int t = (threadIdx.x >= off) ? s[threadIdx.x - off] : 0;
        __syncthreads();
        s[threadIdx.x] += t;
        __syncthreads();
    }
    if (threadIdx.x < nb) bsum[threadIdx.x] = s[threadIdx.x];
}

__global__ __launch_bounds__(256) void scan_c(int* __restrict__ incl_off,
                                              const int* __restrict__ cnt,
                                              const int* __restrict__ bsum) {
    int i = blockIdx.x * 256 + threadIdx.x;
    if (i >= N_NODES) return;
    int base = (blockIdx.x > 0) ? bsum[blockIdx.x - 1] : 0;
    incl_off[i] = incl_off[i] - cnt[i] + base;
}

__global__ __launch_bounds__(256) void cfill_kernel(const int* __restrict__ src,
                                                    const int* __restrict__ dst,
                                                    const int* __restrict__ off,
                                                    int* __restrict__ cur,
                                                    int* __restrict__ lst) {
    int i = blockIdx.x * 256 + threadIdx.x;
    if (i >= N_EDGES) return;
    int d = dst[i];
    int pos = atomicAdd(cur + d, 1);
    lst[off[d] + pos] = src[i];
}

// ---------------- z = h @ W^T via bf16 MFMA, fp32 accumulate, bf16 OUTPUT.
// Operand swap vs r7: A = W rows (m = out-dim), B = h rows (n = node).
// D then maps node->col(lane) and 4 consecutive DIMS -> the 4 acc regs, so the
// epilogue packs acc into ONE dwordx2 store per tile (8 stores/wave vs 32
// scalar store_shorts in r7..r11). Loads unchanged: both fragments contiguous.
__global__ __launch_bounds__(256) void gemm_kernel(const float* __restrict__ h,
                                                   const unsigned short* __restrict__ Wb,
                                                   unsigned short* __restrict__ zb) {
    int wave = blockIdx.x * 4 + (threadIdx.x >> 6);
    if (wave >= N_NODES / 16) return;
    int lane = threadIdx.x & 63;
    int lo = lane & 15;
    int hi = lane >> 4;
    long node0 = (long)wave * 16;

    // stationary B-fragment: B[k=hi*8+j][n=lo] = h[node0+lo][kt*32+hi*8+j]
    bf16x8 hfrag[4];
    const float* hrow = h + (node0 + lo) * DIM;
    #pragma unroll
    for (int kt = 0; kt < 4; ++kt) {
        const float* ap = hrow + kt * 32 + hi * 8;
        float4 f0 = *(const float4*)ap;
        float4 f1 = *(const float4*)(ap + 4);
        bf16x8 a;
        a[0] = f2bf(f0.x); a[1] = f2bf(f0.y); a[2] = f2bf(f0.z); a[3] = f2bf(f0.w);
        a[4] = f2bf(f1.x); a[5] = f2bf(f1.y); a[6] = f2bf(f1.z); a[7] = f2bf(f1.w);
        hfrag[kt] = a;
    }

    #pragma unroll
    for (int mt = 0; mt < 8; ++mt) {      // 8 tiles of 16 output dims
        f32x4 acc = {0.f, 0.f, 0.f, 0.f};
        // A[m=lo][k=hi*8+j] = W[mt*16+lo][k]  (contiguous 16B from Wb)
        const unsigned short* wrow = Wb + (mt * 16 + lo) * DIM + hi * 8;
        #pragma unroll
        for (int kt = 0; kt < 4; ++kt) {
            bf16x8 w = *(const bf16x8*)(wrow + kt * 32);
            acc = __builtin_amdgcn_mfma_f32_16x16x32_bf16(w, hfrag[kt], acc, 0, 0, 0);
        }
        // D: col=lo -> node, row=hi*4+r -> dim mt*16+hi*4+r (4 consecutive dims)
        unsigned u0 = (unsigned)(unsigned short)f2bf(acc[0]);
        unsigned u1 = (unsigned)(unsigned short)f2bf(acc[1]);
        unsigned u2 = (unsigned)(unsigned short)f2bf(acc[2]);
        unsigned u3 = (unsigned)(unsigned short)f2bf(acc[3]);
        uint2 pk;
        pk.x = u0 | (u1 << 16);
        pk.y = u2 | (u3 << 16);
        *(uint2*)(zb + (node0 + lo) * DIM + mt * 16 + hi * 4) = pk;
    }
}

// ---------------- fused per-node: scores + softmax (no-max; r9 numerics note)
// + gather, bf16 z.  ONE NODE PER 16-LANE QUARTER (4 nodes/wave, 16/block):
// eliminates the cross-quarter combine (27 ops/node) and the q==0-only write;
// all 64 lanes write output. Inner loop bound is divergent (per-quarter deg) —
// exec-masking idles finished quarters; __shfl pulls from resident lanes.
__global__ __launch_bounds__(256) void node_kernel(const unsigned short* __restrict__ zb,
                                                   const int* __restrict__ lst,
                                                   const int* __restrict__ off,
                                                   const int* __restrict__ degp,
                                                   int stride,
                                                   const float* __restrict__ beta,
                                                   float* __restrict__ out) {
    int node = blockIdx.x * 16 + (threadIdx.x >> 4);
    if (node >= N_NODES) return;
    int lane = threadIdx.x & 63;
    int q = lane >> 4;          // quarter within wave
    int ql = lane & 15;
    int deg = degp[node];
    int start;
    if (stride > 0) {
        if (deg > BCAP) deg = BCAP;   // impossible for Poisson(12); OOB guard
        start = node * stride;
    } else {
        start = off[node];
    }
    float nbet = -beta[0];

    // zd dims ql*8..+7 for this quarter's node
    uint4 zdw = *(const uint4*)(zb + (long)node * DIM + ql * 8);
    float zd[8];
    UNPK(zdw.x, zd[0], zd[1]) UNPK(zdw.y, zd[2], zd[3])
    UNPK(zdw.z, zd[4], zd[5]) UNPK(zdw.w, zd[6], zd[7])

    float sden = 0.0f;
    float acc[8];
    #pragma unroll
    for (int i = 0; i < 8; ++i) acc[i] = 0.0f;

    for (int cb = 0; cb < deg; cb += 16) {
        int nch = deg - cb;
        if (nch > 16) nch = 16;
        // lane ql holds src of this node's edge slot cb+ql
        int sj = (ql < nch) ? lst[start + cb + ql] : 0;

        for (int j = 0; j < nch; ++j) {          // divergent bound, exec-masked
            int s = __shfl(sj, (q << 4) | j, 64);
            uint4 aw = *(const uint4*)(zb + (long)s * DIM + ql * 8);
            float a[8];
            UNPK(aw.x, a[0], a[1]) UNPK(aw.y, a[2], a[3])
            UNPK(aw.z, a[4], a[5]) UNPK(aw.w, a[6], a[7])

            float p = 0.0f;
            #pragma unroll
            for (int i = 0; i < 8; ++i) {
                float d = a[i] - zd[i];
                p += d * d;
            }
            p = row_sum16(p);                    // full ||z_s - z_d||^2, all 16 lanes
            float w = __expf(nbet * __builtin_amdgcn_sqrtf(p + 1e-12f));
            sden += w;
            #pragma unroll
            for (int i = 0; i < 8; ++i) acc[i] += w * a[i];
        }
    }

    float inv = (deg > 0) ? __builtin_amdgcn_rcpf(sden) : 0.0f;
    float* orow = out + (long)node * DIM + ql * 8;
    *(float4*)orow =
        make_float4(acc[0] * inv, acc[1] * inv, acc[2] * inv, acc[3] * inv);
    *(float4*)(orow + 4) =
        make_float4(acc[4] * inv, acc[5] * inv, acc[6] * inv, acc[7] * inv);
}

extern "C" void kernel_launch(void* const* d_in, const int* in_sizes, int n_in,
                              void* d_out, int out_size, void* d_ws, size_t ws_size,
                              hipStream_t stream) {
    const float* h    = (const float*)d_in[0];
    const float* W    = (const float*)d_in[1];
    const float* beta = (const float*)d_in[2];
    const int* src    = (const int*)d_in[3];
    const int* dst    = (const int*)d_in[4];
    float* out = (float*)d_out;

    // workspace (4B word units).  zb = 50000*128 bf16 = 6.4M shorts = 3.2M WORDS
    //   zb   words [0, 3.2M)
    //   lst  words [3.2M, 3.2M+L)       bucket 3.2M or csr 600k
    //   cnt / cur / off / bsum / Wb after
    const size_t bucket_total = (3200000ull + 3200000 + 150000 + 256 + 8192) * 4;
    const bool use_bucket = ws_size >= bucket_total;
    const size_t lst_len = use_bucket ? 3200000 : 600000;

    float* ws  = (float*)d_ws;
    unsigned short* zb = (unsigned short*)ws;           // 3,200,000 words
    int* lst   = (int*)(ws + 3200000);                  // bucket 3.2M or csr 600k
    int* cnt   = (int*)(ws + 3200000 + lst_len);        // 50,000
    int* cur   = cnt + 50000;                           // 50,000
    int* off   = cur + 50000;                           // 50,000
    int* bsum  = off + 50000;                           //    256
    unsigned short* Wb = (unsigned short*)(bsum + 256); // 16,384 bf16 (8,192 words)

    const int gemm_blocks = (N_NODES / 16 + 3) / 4;     // 3125 waves -> 782 blocks
    const int node_blocks = (N_NODES + 15) / 16;        // 16 nodes/block -> 3125

    prep_kernel<<<196, 256, 0, stream>>>(W, Wb, cur, cnt);
    if (use_bucket) {
        bfill_kernel<<<(N_EDGES + 255) / 256, 256, 0, stream>>>(src, dst, cur, lst);
        gemm_kernel<<<gemm_blocks, 256, 0, stream>>>(h, Wb, zb);
        node_kernel<<<node_blocks, 256, 0, stream>>>(zb, lst, cur /*dummy*/, cur, BCAP,
                                                     beta, out);
    } else {
        count_kernel<<<(N_EDGES + 255) / 256, 256, 0, stream>>>(dst, cnt);
        scan_a<<<196, 256, 0, stream>>>(cnt, off, bsum);
        scan_b<<<1, 256, 0, stream>>>(bsum, 196);
        scan_c<<<196, 256, 0, stream>>>(off, cnt, bsum);
        cfill_kernel<<<(N_EDGES + 255) / 256, 256, 0, stream>>>(src, dst, off, cur, lst);
        gemm_kernel<<<gemm_blocks, 256, 0, stream>>>(h, Wb, zb);
        node_kernel<<<node_blocks, 256, 0, stream>>>(zb, lst, off, cnt, 0, beta, out);
    }
}